// Round 5
// baseline (501.821 us; speedup 1.0000x reference)
//
#include <hip/hip_runtime.h>

#define BB 64
#define HH 128
#define CC 1024
#define QQ 128

typedef unsigned short u16;
typedef unsigned int u32;

__device__ __forceinline__ float b2f(u16 u) {
  union { float f; u32 i; } v; v.i = ((u32)u) << 16; return v.f;
}
__device__ __forceinline__ float lo2f(u32 u) {
  union { float f; u32 i; } v; v.i = u << 16; return v.f;
}
__device__ __forceinline__ float hi2f(u32 u) {
  union { float f; u32 i; } v; v.i = u & 0xFFFF0000u; return v.f;
}
__device__ __forceinline__ u16 f2b(float f) {
  union { float f; u32 i; } v; v.f = f;
  u32 r = v.i + 0x7FFFu + ((v.i >> 16) & 1u);   // RNE
  return (u16)(r >> 16);
}

// ---------------------------------------------------------------------------
// K1: s[b,i,j] = cwc[i] + qwq[j] + sum_h c[i,h]*w_cq[h]*q[j,h], softmax over i
// (per column j). Writes s1 transposed as bf16: s1ws[b][j][i].
// Block: one (b, 16-j group), 256 threads, thread owns i = 4*tid..4*tid+3.
// ---------------------------------------------------------------------------
__global__ __launch_bounds__(256) void k1_s_softmax(
    const float* __restrict__ ctx, const float* __restrict__ qst,
    const float* __restrict__ w, u16* __restrict__ s1) {
  const int b = blockIdx.y;
  const int j0 = blockIdx.x * 16;
  const int tid = threadIdx.x;
  const float* cb = ctx + (size_t)b * HH * CC;
  const float* qb = qst + (size_t)b * HH * QQ;

  float dotv[16][4];
  float qwq[16];
  float cwc[4] = {0.f, 0.f, 0.f, 0.f};
#pragma unroll
  for (int jj = 0; jj < 16; ++jj) {
    qwq[jj] = 0.f;
    dotv[jj][0] = dotv[jj][1] = dotv[jj][2] = dotv[jj][3] = 0.f;
  }

  for (int h = 0; h < HH; ++h) {
    const float4 cv = *(const float4*)(cb + (size_t)h * CC + tid * 4);
    float c0 = cv.x, c1 = cv.y, c2 = cv.z, c3 = cv.w;
    float wqv = w[h], wcv = w[HH + h], wcqv = w[2 * HH + h];
    cwc[0] += c0 * wcv; cwc[1] += c1 * wcv;
    cwc[2] += c2 * wcv; cwc[3] += c3 * wcv;
    float t0 = c0 * wcqv, t1 = c1 * wcqv, t2 = c2 * wcqv, t3 = c3 * wcqv;
    const float4* qrow = (const float4*)(qb + (size_t)h * QQ + j0);
    float4 q0 = qrow[0], q1 = qrow[1], q2 = qrow[2], q3 = qrow[3];
    float qv[16] = {q0.x, q0.y, q0.z, q0.w, q1.x, q1.y, q1.z, q1.w,
                    q2.x, q2.y, q2.z, q2.w, q3.x, q3.y, q3.z, q3.w};
#pragma unroll
    for (int jj = 0; jj < 16; ++jj) {
      qwq[jj] += qv[jj] * wqv;
      dotv[jj][0] += t0 * qv[jj];
      dotv[jj][1] += t1 * qv[jj];
      dotv[jj][2] += t2 * qv[jj];
      dotv[jj][3] += t3 * qv[jj];
    }
  }
#pragma unroll
  for (int jj = 0; jj < 16; ++jj) {
    float base = qwq[jj];
    dotv[jj][0] += cwc[0] + base;
    dotv[jj][1] += cwc[1] + base;
    dotv[jj][2] += cwc[2] + base;
    dotv[jj][3] += cwc[3] + base;
  }

  __shared__ float red[16 * 256];
  __shared__ float red2[16 * 16];
  __shared__ float bc[16];
  const int rj = tid >> 4, rs = tid & 15;

  // ---- max over i per column jj ----
#pragma unroll
  for (int jj = 0; jj < 16; ++jj) {
    float m = fmaxf(fmaxf(dotv[jj][0], dotv[jj][1]),
                    fmaxf(dotv[jj][2], dotv[jj][3]));
    red[jj * 256 + tid] = m;
  }
  __syncthreads();
  {
    float m = red[rj * 256 + rs * 16];
#pragma unroll
    for (int g = 1; g < 16; ++g) m = fmaxf(m, red[rj * 256 + rs * 16 + g]);
    red2[rj * 16 + rs] = m;
  }
  __syncthreads();
  if (tid < 16) {
    float m = red2[tid * 16];
#pragma unroll
    for (int g = 1; g < 16; ++g) m = fmaxf(m, red2[tid * 16 + g]);
    bc[tid] = m;
  }
  __syncthreads();

  // ---- exp + sum ----
#pragma unroll
  for (int jj = 0; jj < 16; ++jj) {
    float mj = bc[jj];
    float e0 = __expf(dotv[jj][0] - mj);
    float e1 = __expf(dotv[jj][1] - mj);
    float e2 = __expf(dotv[jj][2] - mj);
    float e3 = __expf(dotv[jj][3] - mj);
    dotv[jj][0] = e0; dotv[jj][1] = e1; dotv[jj][2] = e2; dotv[jj][3] = e3;
    red[jj * 256 + tid] = e0 + e1 + e2 + e3;
  }
  __syncthreads();
  {
    float s = 0.f;
#pragma unroll
    for (int g = 0; g < 16; ++g) s += red[rj * 256 + rs * 16 + g];
    red2[rj * 16 + rs] = s;
  }
  __syncthreads();
  if (tid < 16) {
    float s = 0.f;
#pragma unroll
    for (int g = 0; g < 16; ++g) s += red2[tid * 16 + g];
    bc[tid] = 1.0f / s;
  }
  __syncthreads();

  u16* srow = s1 + ((size_t)b * QQ + j0) * CC + tid * 4;
#pragma unroll
  for (int jj = 0; jj < 16; ++jj) {
    float inv = bc[jj];
    uint2 pk;
    pk.x = (u32)f2b(dotv[jj][0] * inv) | ((u32)f2b(dotv[jj][1] * inv) << 16);
    pk.y = (u32)f2b(dotv[jj][2] * inv) | ((u32)f2b(dotv[jj][3] * inv) << 16);
    *(uint2*)(srow + (size_t)jj * CC) = pk;
  }
}

// ---------------------------------------------------------------------------
// K2: t[b,j,h] = sum_i s1ws[b][j][i] * ctx[b][h][i], full-K (1024), one
// 64x64 (j,h) tile per block; grid (4, BB) = 256 blocks.
// Thread (tj=tid>>4, th=tid&15) owns j=j0+tj+16jj, h=h0+th+16hh (jj,hh<4).
// ---------------------------------------------------------------------------
__global__ __launch_bounds__(256) void k2_t(
    const float* __restrict__ ctx, const u16* __restrict__ s1,
    float* __restrict__ t) {
  const int b = blockIdx.y;
  const int tz = blockIdx.x;
  const int j0 = (tz & 1) * 64;
  const int h0 = (tz >> 1) * 64;
  const int tid = threadIdx.x;
  const int tj = tid >> 4, th = tid & 15;
  __shared__ float sA[64 * 33];
  __shared__ float sB[64 * 33];
  float acc[4][4];
#pragma unroll
  for (int jj = 0; jj < 4; ++jj)
#pragma unroll
    for (int hh = 0; hh < 4; ++hh) acc[jj][hh] = 0.f;

  const int r = tid >> 2;        // 0..63 (staging row)
  const int sg = (tid & 3) * 8;  // 0,8,16,24 (staging col group)
  const u16* sbase = s1 + ((size_t)b * QQ + j0 + r) * CC + sg;
  const float* cbase = ctx + ((size_t)b * HH + h0 + r) * CC + sg;

  for (int ib = 0; ib < CC; ib += 32) {
    __syncthreads();
    {
      uint4 sv = *(const uint4*)(sbase + ib);  // 8 bf16
      float* a = &sA[r * 33 + sg];
      a[0] = lo2f(sv.x); a[1] = hi2f(sv.x);
      a[2] = lo2f(sv.y); a[3] = hi2f(sv.y);
      a[4] = lo2f(sv.z); a[5] = hi2f(sv.z);
      a[6] = lo2f(sv.w); a[7] = hi2f(sv.w);
      float4 c0 = *(const float4*)(cbase + ib);
      float4 c1 = *(const float4*)(cbase + ib + 4);
      float* bptr = &sB[r * 33 + sg];
      bptr[0] = c0.x; bptr[1] = c0.y; bptr[2] = c0.z; bptr[3] = c0.w;
      bptr[4] = c1.x; bptr[5] = c1.y; bptr[6] = c1.z; bptr[7] = c1.w;
    }
    __syncthreads();
#pragma unroll 4
    for (int ii = 0; ii < 32; ++ii) {
      float av[4], bv[4];
#pragma unroll
      for (int jj = 0; jj < 4; ++jj) av[jj] = sA[(tj + 16 * jj) * 33 + ii];
#pragma unroll
      for (int hh = 0; hh < 4; ++hh) bv[hh] = sB[(th + 16 * hh) * 33 + ii];
#pragma unroll
      for (int jj = 0; jj < 4; ++jj)
#pragma unroll
        for (int hh = 0; hh < 4; ++hh) acc[jj][hh] += av[jj] * bv[hh];
    }
  }
  float* tp = t + (size_t)b * QQ * HH;
#pragma unroll
  for (int jj = 0; jj < 4; ++jj)
#pragma unroll
    for (int hh = 0; hh < 4; ++hh)
      tp[(size_t)(j0 + tj + 16 * jj) * HH + (h0 + th + 16 * hh)] = acc[jj][hh];
}

// ---------------------------------------------------------------------------
// K3: a[i,h] = sum_j s1ws[b][j][i]*q[b][h][j]
//     bb[i,h] = sum_j s1ws[b][j][i]*t[b][j][h]
// out[b][ch][i] (fp32): ch=h -> c; 128+h -> a; 256+h -> c*a; 384+h -> c*bb.
// Thread owns one i; s1 column (128) in VGPRs; h staged 8 at a time.
// ---------------------------------------------------------------------------
__global__ __launch_bounds__(256) void k3_out(
    const float* __restrict__ ctx, const float* __restrict__ qst,
    const u16* __restrict__ s1, const float* __restrict__ t,
    float* __restrict__ out) {
  const int b = blockIdx.y;
  const int tid = threadIdx.x;
  const int i = blockIdx.x * 256 + tid;

  float s1col[128];
#pragma unroll
  for (int j = 0; j < 128; ++j)
    s1col[j] = b2f(s1[((size_t)b * QQ + j) * CC + i]);

  __shared__ float Qch[8 * 128];
  __shared__ float Tch[8 * 128];

  for (int h0 = 0; h0 < HH; h0 += 8) {
    __syncthreads();
    {  // stage Qch[hc][j] = q[b][h0+hc][j]
      int hc = tid >> 5;
      int col = (tid & 31) * 4;
      float4 qr = *(const float4*)(qst + ((size_t)b * HH + h0 + hc) * QQ + col);
      Qch[hc * 128 + col + 0] = qr.x;
      Qch[hc * 128 + col + 1] = qr.y;
      Qch[hc * 128 + col + 2] = qr.z;
      Qch[hc * 128 + col + 3] = qr.w;
    }
    {  // stage Tch[hc][j] = t[b][j][h0+hc]
#pragma unroll
      for (int k = 0; k < 4; ++k) {
        int e = tid * 4 + k;  // 0..1023
        int jq = e >> 3, hc = e & 7;
        Tch[hc * 128 + jq] = t[((size_t)b * QQ + jq) * HH + h0 + hc];
      }
    }
    __syncthreads();

    for (int hc = 0; hc < 8; ++hc) {
      float aA = 0.f, aB = 0.f;
#pragma unroll
      for (int j4 = 0; j4 < 32; ++j4) {
        float4 qv = *(const float4*)&Qch[hc * 128 + j4 * 4];
        float4 tv = *(const float4*)&Tch[hc * 128 + j4 * 4];
        aA += s1col[4 * j4 + 0] * qv.x + s1col[4 * j4 + 1] * qv.y +
              s1col[4 * j4 + 2] * qv.z + s1col[4 * j4 + 3] * qv.w;
        aB += s1col[4 * j4 + 0] * tv.x + s1col[4 * j4 + 1] * tv.y +
              s1col[4 * j4 + 2] * tv.z + s1col[4 * j4 + 3] * tv.w;
      }
      int h = h0 + hc;
      float cval = ctx[((size_t)b * HH + h) * CC + i];
      size_t ob = (size_t)b * 4 * HH * CC + i;
      out[ob + (size_t)h * CC] = cval;
      out[ob + (size_t)(HH + h) * CC] = aA;
      out[ob + (size_t)(2 * HH + h) * CC] = cval * aA;
      out[ob + (size_t)(3 * HH + h) * CC] = cval * aB;
    }
  }
}

extern "C" void kernel_launch(void* const* d_in, const int* in_sizes, int n_in,
                              void* d_out, int out_size, void* d_ws, size_t ws_size,
                              hipStream_t stream) {
  // Map inputs by element count (all three are distinct).
  const float* ctx = (const float*)d_in[0];
  const float* qst = (const float*)d_in[1];
  const float* w = (const float*)d_in[2];
  for (int k = 0; k < n_in; ++k) {
    if (in_sizes[k] == BB * HH * CC) ctx = (const float*)d_in[k];
    else if (in_sizes[k] == BB * HH * QQ) qst = (const float*)d_in[k];
    else if (in_sizes[k] == 3 * HH) w = (const float*)d_in[k];
  }
  float* out = (float*)d_out;

  // Workspace: s1 bf16 (16 MiB) + t fp32 (4 MiB) = 20 MiB total.
  u16* s1 = (u16*)d_ws;
  float* t = (float*)((char*)d_ws + (size_t)BB * QQ * CC * sizeof(u16));

  k1_s_softmax<<<dim3(QQ / 16, BB), 256, 0, stream>>>(ctx, qst, w, s1);
  k2_t<<<dim3(4, BB), 256, 0, stream>>>(ctx, s1, t);
  k3_out<<<dim3(CC / 256, BB), 256, 0, stream>>>(ctx, qst, s1, t, out);
}

// Round 6
// 296.461 us; speedup vs baseline: 1.6927x; 1.6927x over previous
//
#include <hip/hip_runtime.h>

#define BB 64
#define HH 128
#define CC 1024
#define QQ 128

typedef unsigned short u16;
typedef unsigned int u32;

__device__ __forceinline__ float lo2f(u32 u) {
  union { float f; u32 i; } v; v.i = u << 16; return v.f;
}
__device__ __forceinline__ float hi2f(u32 u) {
  union { float f; u32 i; } v; v.i = u & 0xFFFF0000u; return v.f;
}
__device__ __forceinline__ u16 f2b(float f) {
  union { float f; u32 i; } v; v.f = f;
  u32 r = v.i + 0x7FFFu + ((v.i >> 16) & 1u);   // RNE
  return (u16)(r >> 16);
}

// ---------------------------------------------------------------------------
// K1: s[b,i,j] = cwc[i] + qwq[j] + sum_h c[i,h]*w_cq[h]*q[j,h], softmax over i
// (per column j). Writes s1 transposed as bf16: s1ws[b][j][i].
// Block: one (b, 16-j group), 512 threads, thread owns i = 2*tid, 2*tid+1.
// 512 blocks x 8 waves = 16 waves/CU for load-latency hiding.
// ---------------------------------------------------------------------------
__global__ __launch_bounds__(512) void k1_s_softmax(
    const float* __restrict__ ctx, const float* __restrict__ qst,
    const float* __restrict__ w, u16* __restrict__ s1) {
  const int b = blockIdx.y;
  const int j0 = blockIdx.x * 16;
  const int tid = threadIdx.x;
  const float* cb = ctx + (size_t)b * HH * CC;
  const float* qb = qst + (size_t)b * HH * QQ;

  float dotv[16][2];
  float qwq[16];
  float cwc[2] = {0.f, 0.f};
#pragma unroll
  for (int jj = 0; jj < 16; ++jj) {
    qwq[jj] = 0.f;
    dotv[jj][0] = dotv[jj][1] = 0.f;
  }

  for (int h = 0; h < HH; ++h) {
    const float2 cv = *(const float2*)(cb + (size_t)h * CC + tid * 2);
    float c0 = cv.x, c1 = cv.y;
    float wqv = w[h], wcv = w[HH + h], wcqv = w[2 * HH + h];
    cwc[0] += c0 * wcv; cwc[1] += c1 * wcv;
    float t0 = c0 * wcqv, t1 = c1 * wcqv;
    const float4* qrow = (const float4*)(qb + (size_t)h * QQ + j0);
    float4 q0 = qrow[0], q1 = qrow[1], q2 = qrow[2], q3 = qrow[3];
    float qv[16] = {q0.x, q0.y, q0.z, q0.w, q1.x, q1.y, q1.z, q1.w,
                    q2.x, q2.y, q2.z, q2.w, q3.x, q3.y, q3.z, q3.w};
#pragma unroll
    for (int jj = 0; jj < 16; ++jj) {
      qwq[jj] += qv[jj] * wqv;
      dotv[jj][0] += t0 * qv[jj];
      dotv[jj][1] += t1 * qv[jj];
    }
  }
#pragma unroll
  for (int jj = 0; jj < 16; ++jj) {
    float base = qwq[jj];
    dotv[jj][0] += cwc[0] + base;
    dotv[jj][1] += cwc[1] + base;
  }

  __shared__ float red[16 * 512];
  __shared__ float red2[16 * 32];
  __shared__ float bc[16];
  const int rj = tid >> 5, rs = tid & 31;

  // ---- max over i per column jj ----
#pragma unroll
  for (int jj = 0; jj < 16; ++jj)
    red[jj * 512 + tid] = fmaxf(dotv[jj][0], dotv[jj][1]);
  __syncthreads();
  {
    float m = red[rj * 512 + rs * 16];
#pragma unroll
    for (int g = 1; g < 16; ++g) m = fmaxf(m, red[rj * 512 + rs * 16 + g]);
    red2[rj * 32 + rs] = m;
  }
  __syncthreads();
  if (tid < 16) {
    float m = red2[tid * 32];
#pragma unroll
    for (int g = 1; g < 32; ++g) m = fmaxf(m, red2[tid * 32 + g]);
    bc[tid] = m;
  }
  __syncthreads();

  // ---- exp + sum ----
#pragma unroll
  for (int jj = 0; jj < 16; ++jj) {
    float mj = bc[jj];
    float e0 = __expf(dotv[jj][0] - mj);
    float e1 = __expf(dotv[jj][1] - mj);
    dotv[jj][0] = e0; dotv[jj][1] = e1;
    red[jj * 512 + tid] = e0 + e1;
  }
  __syncthreads();
  {
    float s = 0.f;
#pragma unroll
    for (int g = 0; g < 16; ++g) s += red[rj * 512 + rs * 16 + g];
    red2[rj * 32 + rs] = s;
  }
  __syncthreads();
  if (tid < 16) {
    float s = 0.f;
#pragma unroll
    for (int g = 0; g < 32; ++g) s += red2[tid * 32 + g];
    bc[tid] = 1.0f / s;
  }
  __syncthreads();

  u16* srow = s1 + ((size_t)b * QQ + j0) * CC + tid * 2;
#pragma unroll
  for (int jj = 0; jj < 16; ++jj) {
    float inv = bc[jj];
    u32 pk = (u32)f2b(dotv[jj][0] * inv) | ((u32)f2b(dotv[jj][1] * inv) << 16);
    *(u32*)(srow + (size_t)jj * CC) = pk;
  }
}

// ---------------------------------------------------------------------------
// K2: t[b,j,h] = sum_i s1ws[b][j][i] * ctx[b][h][i], split-K x4 (K=256 each),
// 64x64 (j,h) tile per block; grid (16, BB) = 1024 blocks; atomicAdd into t.
// t must be zeroed before launch (hipMemsetAsync in kernel_launch).
// ---------------------------------------------------------------------------
__global__ __launch_bounds__(256) void k2_t(
    const float* __restrict__ ctx, const u16* __restrict__ s1,
    float* __restrict__ t) {
  const int b = blockIdx.y;
  const int tz = blockIdx.x;
  const int tile = tz & 3;
  const int z = tz >> 2;              // k-split 0..3
  const int j0 = (tile & 1) * 64;
  const int h0 = (tile >> 1) * 64;
  const int tid = threadIdx.x;
  const int tj = tid >> 4, th = tid & 15;
  __shared__ float sA[64 * 33];
  __shared__ float sB[64 * 33];
  float acc[4][4];
#pragma unroll
  for (int jj = 0; jj < 4; ++jj)
#pragma unroll
    for (int hh = 0; hh < 4; ++hh) acc[jj][hh] = 0.f;

  const int r = tid >> 2;        // 0..63 (staging row)
  const int sg = (tid & 3) * 8;  // 0,8,16,24 (staging col group)
  const u16* sbase = s1 + ((size_t)b * QQ + j0 + r) * CC + sg;
  const float* cbase = ctx + ((size_t)b * HH + h0 + r) * CC + sg;

  const int ib0 = z * 256;
  for (int ib = ib0; ib < ib0 + 256; ib += 32) {
    __syncthreads();
    {
      uint4 sv = *(const uint4*)(sbase + ib);  // 8 bf16
      float* a = &sA[r * 33 + sg];
      a[0] = lo2f(sv.x); a[1] = hi2f(sv.x);
      a[2] = lo2f(sv.y); a[3] = hi2f(sv.y);
      a[4] = lo2f(sv.z); a[5] = hi2f(sv.z);
      a[6] = lo2f(sv.w); a[7] = hi2f(sv.w);
      float4 c0 = *(const float4*)(cbase + ib);
      float4 c1 = *(const float4*)(cbase + ib + 4);
      float* bptr = &sB[r * 33 + sg];
      bptr[0] = c0.x; bptr[1] = c0.y; bptr[2] = c0.z; bptr[3] = c0.w;
      bptr[4] = c1.x; bptr[5] = c1.y; bptr[6] = c1.z; bptr[7] = c1.w;
    }
    __syncthreads();
#pragma unroll 4
    for (int ii = 0; ii < 32; ++ii) {
      float av[4], bv[4];
#pragma unroll
      for (int jj = 0; jj < 4; ++jj) av[jj] = sA[(tj + 16 * jj) * 33 + ii];
#pragma unroll
      for (int hh = 0; hh < 4; ++hh) bv[hh] = sB[(th + 16 * hh) * 33 + ii];
#pragma unroll
      for (int jj = 0; jj < 4; ++jj)
#pragma unroll
        for (int hh = 0; hh < 4; ++hh) acc[jj][hh] += av[jj] * bv[hh];
    }
  }
  float* tp = t + (size_t)b * QQ * HH;
#pragma unroll
  for (int jj = 0; jj < 4; ++jj)
#pragma unroll
    for (int hh = 0; hh < 4; ++hh)
      atomicAdd(&tp[(size_t)(j0 + tj + 16 * jj) * HH + (h0 + th + 16 * hh)],
                acc[jj][hh]);
}

// ---------------------------------------------------------------------------
// K3: two GEMMs sharing the A-operand (s1):
//   a[i,h]  = sum_j s1t[j,i] * q[h,j]
//   bb[i,h] = sum_j s1t[j,i] * t[j,h]
// Block: 64i x 64h tile, 256 threads, thread owns 4i x 4h x 2 accumulators.
// K=j=128 staged in LDS chunks of 32 (sA from s1 bf16, sQ = q transposed,
// sT = t direct copy). Grid (32, BB) = 2048 blocks.
// out[b][ch][i] (fp32): ch=h -> c; 128+h -> a; 256+h -> c*a; 384+h -> c*bb.
// ---------------------------------------------------------------------------
__global__ __launch_bounds__(256) void k3_out(
    const float* __restrict__ ctx, const float* __restrict__ qst,
    const u16* __restrict__ s1, const float* __restrict__ t,
    float* __restrict__ out) {
  const int b = blockIdx.y;
  const int i0 = (blockIdx.x >> 1) * 64;   // 16 i-tiles
  const int h0 = (blockIdx.x & 1) * 64;    // 2 h-tiles
  const int tid = threadIdx.x;
  const int ti = tid & 15;    // i = i0 + ti*4 + (0..3)
  const int th2 = tid >> 4;   // h = h0 + th2*4 + (0..3)

  __shared__ float sA[32][65];
  __shared__ float sQ[32][65];
  __shared__ float sT[32][65];

  float accA[4][4], accB[4][4];
#pragma unroll
  for (int ii = 0; ii < 4; ++ii)
#pragma unroll
    for (int hh = 0; hh < 4; ++hh) { accA[ii][hh] = 0.f; accB[ii][hh] = 0.f; }

  for (int jc = 0; jc < QQ; jc += 32) {
    __syncthreads();
    {  // sA[j'][i'] from s1[b][jc+j'][i0+i'] (bf16 -> f32); 32x64
      int rr = tid >> 3, col = (tid & 7) * 8;
      uint4 v = *(const uint4*)(s1 + ((size_t)b * QQ + jc + rr) * CC + i0 + col);
      float* dst = &sA[rr][col];
      dst[0] = lo2f(v.x); dst[1] = hi2f(v.x);
      dst[2] = lo2f(v.y); dst[3] = hi2f(v.y);
      dst[4] = lo2f(v.z); dst[5] = hi2f(v.z);
      dst[6] = lo2f(v.w); dst[7] = hi2f(v.w);
    }
    {  // sT[j'][h'] from t[b][jc+j'][h0+h']; 32x64 direct copy
      int rr = tid >> 3, col = (tid & 7) * 8;
      const float* p = t + ((size_t)b * QQ + jc + rr) * HH + h0 + col;
      float4 v0 = *(const float4*)p;
      float4 v1 = *(const float4*)(p + 4);
      float* dst = &sT[rr][col];
      dst[0] = v0.x; dst[1] = v0.y; dst[2] = v0.z; dst[3] = v0.w;
      dst[4] = v1.x; dst[5] = v1.y; dst[6] = v1.z; dst[7] = v1.w;
    }
    {  // sQ[j'][h'] = q[b][h0+h'][jc+j'] (transpose); 64 rows x 32 j
      int hh = tid >> 2, jo = (tid & 3) * 8;
      const float* p = qst + ((size_t)b * HH + h0 + hh) * QQ + jc + jo;
      float4 v0 = *(const float4*)p;
      float4 v1 = *(const float4*)(p + 4);
      sQ[jo + 0][hh] = v0.x; sQ[jo + 1][hh] = v0.y;
      sQ[jo + 2][hh] = v0.z; sQ[jo + 3][hh] = v0.w;
      sQ[jo + 4][hh] = v1.x; sQ[jo + 5][hh] = v1.y;
      sQ[jo + 6][hh] = v1.z; sQ[jo + 7][hh] = v1.w;
    }
    __syncthreads();

#pragma unroll 8
    for (int kk = 0; kk < 32; ++kk) {
      float4 avv = *(const float4*)&sA[kk][ti * 4];
      float4 qvv = *(const float4*)&sQ[kk][th2 * 4];
      float4 tvv = *(const float4*)&sT[kk][th2 * 4];
      float av[4] = {avv.x, avv.y, avv.z, avv.w};
      float qv[4] = {qvv.x, qvv.y, qvv.z, qvv.w};
      float tv[4] = {tvv.x, tvv.y, tvv.z, tvv.w};
#pragma unroll
      for (int ii = 0; ii < 4; ++ii)
#pragma unroll
        for (int hh = 0; hh < 4; ++hh) {
          accA[ii][hh] += av[ii] * qv[hh];
          accB[ii][hh] += av[ii] * tv[hh];
        }
    }
  }

  // Epilogue: 4 h-rows, each with 4 output sections.
#pragma unroll
  for (int hh = 0; hh < 4; ++hh) {
    int h = h0 + th2 * 4 + hh;
    float4 cv = *(const float4*)(ctx + ((size_t)b * HH + h) * CC + i0 + ti * 4);
    float4 oA = {accA[0][hh], accA[1][hh], accA[2][hh], accA[3][hh]};
    float4 oB = {accB[0][hh], accB[1][hh], accB[2][hh], accB[3][hh]};
    float4 cA = {cv.x * oA.x, cv.y * oA.y, cv.z * oA.z, cv.w * oA.w};
    float4 cB = {cv.x * oB.x, cv.y * oB.y, cv.z * oB.z, cv.w * oB.w};
    size_t ob = (size_t)b * 4 * HH * CC + i0 + ti * 4;
    *(float4*)(out + ob + (size_t)h * CC) = cv;
    *(float4*)(out + ob + (size_t)(HH + h) * CC) = oA;
    *(float4*)(out + ob + (size_t)(2 * HH + h) * CC) = cA;
    *(float4*)(out + ob + (size_t)(3 * HH + h) * CC) = cB;
  }
}

extern "C" void kernel_launch(void* const* d_in, const int* in_sizes, int n_in,
                              void* d_out, int out_size, void* d_ws, size_t ws_size,
                              hipStream_t stream) {
  // Map inputs by element count (all three are distinct).
  const float* ctx = (const float*)d_in[0];
  const float* qst = (const float*)d_in[1];
  const float* w = (const float*)d_in[2];
  for (int k = 0; k < n_in; ++k) {
    if (in_sizes[k] == BB * HH * CC) ctx = (const float*)d_in[k];
    else if (in_sizes[k] == BB * HH * QQ) qst = (const float*)d_in[k];
    else if (in_sizes[k] == 3 * HH) w = (const float*)d_in[k];
  }
  float* out = (float*)d_out;

  // Workspace: s1 bf16 (16 MiB) + t fp32 (4 MiB) = 20 MiB total.
  u16* s1 = (u16*)d_ws;
  float* t = (float*)((char*)d_ws + (size_t)BB * QQ * CC * sizeof(u16));

  k1_s_softmax<<<dim3(QQ / 16, BB), 512, 0, stream>>>(ctx, qst, w, s1);
  hipMemsetAsync(t, 0, (size_t)BB * QQ * HH * sizeof(float), stream);
  k2_t<<<dim3(16, BB), 256, 0, stream>>>(ctx, s1, t);
  k3_out<<<dim3(32, BB), 256, 0, stream>>>(ctx, qst, s1, t, out);
}